// Round 5
// baseline (369.615 us; speedup 1.0000x reference)
//
#include <hip/hip_runtime.h>

// MHA: B=4, S=2048, d_model=1024, H=16, d_k=64
// Primary path (ws >= 109 MB): conv3(activations) + conv4(weights) ->
//   fused QKV GEMM (grid z=3, 1536 blocks) -> attn -> out GEMM (64x128 tile).
// Fallback (small ws): R4 sequential path.

#define DMODEL 1024
#define DK     64
#define NH     16
#define BSZ    4
#define SEQ    2048
#define MTOT   (BSZ * SEQ)   // 8192

typedef __attribute__((ext_vector_type(8))) __bf16 bf16x8;
typedef __attribute__((ext_vector_type(4))) float  f32x4;

__device__ inline unsigned short f2bf(float x) {
    union { float f; unsigned u; } v; v.f = x;
    unsigned r = v.u + 0x7FFF + ((v.u >> 16) & 1u);   // RNE
    return (unsigned short)(r >> 16);
}

__device__ inline bf16x8 ld_frag(const unsigned short* p) {
    return __builtin_bit_cast(bf16x8, *(const int4*)p);
}

union V8 { int4 v; unsigned short s[8]; };

__device__ inline void gload16(const unsigned short* g, unsigned short* l) {
    __builtin_amdgcn_global_load_lds(
        (const __attribute__((address_space(1))) void*)g,
        (__attribute__((address_space(3))) void*)l, 16, 0, 0);
}

__device__ inline unsigned pack_bf(float lo, float hi) {
    unsigned b0 = __builtin_bit_cast(unsigned, lo) + 0x8000u;
    unsigned b1 = __builtin_bit_cast(unsigned, hi) + 0x8000u;
    return __builtin_amdgcn_perm(b1, b0, 0x07060302u);
}

// ---------------------------------------------------------------------------
// fp32 -> bf16 converters
// ---------------------------------------------------------------------------
__device__ inline void conv_body(const float* __restrict__ src,
                                 unsigned short* __restrict__ dst, int i)
{
    const float4* s = (const float4*)src + (size_t)i * 2;
    float4 a = s[0], b = s[1];
    V8 u;
    u.s[0] = f2bf(a.x); u.s[1] = f2bf(a.y); u.s[2] = f2bf(a.z); u.s[3] = f2bf(a.w);
    u.s[4] = f2bf(b.x); u.s[5] = f2bf(b.y); u.s[6] = f2bf(b.z); u.s[7] = f2bf(b.w);
    ((int4*)dst)[i] = u.v;
}

__global__ __launch_bounds__(256)
void conv_bf16(const float* __restrict__ src, unsigned short* __restrict__ dst)
{
    conv_body(src, dst, blockIdx.x * 256 + threadIdx.x);
}

__global__ __launch_bounds__(256)
void conv3(const float* __restrict__ s0, const float* __restrict__ s1,
           const float* __restrict__ s2, unsigned short* __restrict__ d0,
           unsigned short* __restrict__ d1, unsigned short* __restrict__ d2)
{
    int z = blockIdx.z;
    const float* s = (z == 0) ? s0 : (z == 1) ? s1 : s2;
    unsigned short* d = (z == 0) ? d0 : (z == 1) ? d1 : d2;
    conv_body(s, d, blockIdx.x * 256 + threadIdx.x);
}

__global__ __launch_bounds__(256)
void conv4(const float* __restrict__ s0, const float* __restrict__ s1,
           const float* __restrict__ s2, const float* __restrict__ s3,
           unsigned short* __restrict__ d0, unsigned short* __restrict__ d1,
           unsigned short* __restrict__ d2, unsigned short* __restrict__ d3)
{
    int z = blockIdx.z;
    const float* s = (z == 0) ? s0 : (z == 1) ? s1 : (z == 2) ? s2 : s3;
    unsigned short* d = (z == 0) ? d0 : (z == 1) ? d1 : (z == 2) ? d2 : d3;
    conv_body(s, d, blockIdx.x * 256 + threadIdx.x);
}

// ---------------------------------------------------------------------------
// bf16 GEMM (standalone, fallback): 128x128 tile, gload16, XOR swizzle.
// ---------------------------------------------------------------------------
template<int OUT_F32, int BIAS_ROW>
__global__ __launch_bounds__(256)
void gemm_bt16(const unsigned short* __restrict__ A, const unsigned short* __restrict__ Bt,
               const float* __restrict__ bias, void* __restrict__ Cout,
               int Mdim, int Ndim, int Kdim, float scale)
{
    __shared__ unsigned short As[128 * 64];
    __shared__ unsigned short Bs[128 * 64];

    const int tid  = threadIdx.x;
    const int wave = tid >> 6, lane = tid & 63, quad = lane >> 4, l16 = lane & 15;
    const int wm = wave >> 1, wn = wave & 1;
    const int m0 = blockIdx.x * 128, n0 = blockIdx.y * 128;
    const int srow = lane >> 3, pch = lane & 7;

    f32x4 acc[4][4];
#pragma unroll
    for (int i = 0; i < 4; ++i)
#pragma unroll
        for (int j = 0; j < 4; ++j)
#pragma unroll
            for (int r = 0; r < 4; ++r) acc[i][j][r] = 0.f;

    for (int k0 = 0; k0 < Kdim; k0 += 64) {
#pragma unroll
        for (int rr = 0; rr < 4; ++rr) {
            int row = rr * 32 + wave * 8 + srow;
            int c   = pch ^ (row & 7);
            gload16(A + (size_t)(m0 + row) * Kdim + k0 + c * 8,
                    &As[(size_t)(rr * 32 + wave * 8) * 64]);
        }
#pragma unroll
        for (int rr = 0; rr < 4; ++rr) {
            int row = rr * 32 + wave * 8 + srow;
            int c   = pch ^ (row & 7);
            gload16(Bt + (size_t)(n0 + row) * Kdim + k0 + c * 8,
                    &Bs[(size_t)(rr * 32 + wave * 8) * 64]);
        }
        __syncthreads();

#pragma unroll
        for (int hh = 0; hh < 2; ++hh) {
            bf16x8 af[4], bfr[4];
#pragma unroll
            for (int t = 0; t < 4; ++t) {
                int ra = wm * 64 + t * 16 + l16;
                int pa = (hh * 4 + quad) ^ (l16 & 7);
                af[t] = ld_frag(&As[(size_t)ra * 64 + pa * 8]);
                int rb = wn * 64 + t * 16 + l16;
                bfr[t] = ld_frag(&Bs[(size_t)rb * 64 + pa * 8]);
            }
#pragma unroll
            for (int i = 0; i < 4; ++i)
#pragma unroll
                for (int j = 0; j < 4; ++j)
                    acc[i][j] = __builtin_amdgcn_mfma_f32_16x16x32_bf16(af[i], bfr[j], acc[i][j], 0, 0, 0);
        }
        __syncthreads();
    }

#pragma unroll
    for (int j = 0; j < 4; ++j) {
        int n = n0 + wn * 64 + j * 16 + l16;
        float bcol = BIAS_ROW ? 0.f : bias[n];
#pragma unroll
        for (int i = 0; i < 4; ++i) {
#pragma unroll
            for (int r = 0; r < 4; ++r) {
                int m = m0 + wm * 64 + i * 16 + quad * 4 + r;
                float bv = BIAS_ROW ? bias[m] : bcol;
                float val = (acc[i][j][r] + bv) * scale;
                if (OUT_F32) ((float*)Cout)[(size_t)m * Ndim + n] = val;
                else ((unsigned short*)Cout)[(size_t)m * Ndim + n] = f2bf(val);
            }
        }
    }
}

// ---------------------------------------------------------------------------
// Fused QKV projection GEMM. grid (64, 8, 3):
//  z=0: Qb  = (query@Wq^T + bq) * qscale        m0=bx*128, n0=by*128
//  z=1: Kb  =  key  @Wk^T + bk                  same
//  z=2: VbT = (Wv@value^T + bv[row])            m0=by*128, n0=bx*128, stride MTOT
// ---------------------------------------------------------------------------
__global__ __launch_bounds__(256)
void qkv_gemm(const unsigned short* __restrict__ Qa, const unsigned short* __restrict__ Ka,
              const unsigned short* __restrict__ Va,
              const unsigned short* __restrict__ Wqb, const unsigned short* __restrict__ Wkb,
              const unsigned short* __restrict__ Wvb,
              const float* __restrict__ bq, const float* __restrict__ bk,
              const float* __restrict__ bv,
              unsigned short* __restrict__ Qb, unsigned short* __restrict__ Kb,
              unsigned short* __restrict__ VbT, float qscale)
{
    __shared__ unsigned short As[128 * 64];
    __shared__ unsigned short Bs[128 * 64];

    const int z = blockIdx.z;
    const unsigned short* A  = (z == 0) ? Qa  : (z == 1) ? Ka  : Wvb;
    const unsigned short* Bt = (z == 0) ? Wqb : (z == 1) ? Wkb : Va;
    const float* bias        = (z == 0) ? bq  : (z == 1) ? bk  : bv;
    unsigned short* out      = (z == 0) ? Qb  : (z == 1) ? Kb  : VbT;
    const float scale  = (z == 0) ? qscale : 1.0f;
    const int brow     = (z == 2);
    const int m0       = brow ? blockIdx.y * 128 : blockIdx.x * 128;
    const int n0       = brow ? blockIdx.x * 128 : blockIdx.y * 128;
    const int ostride  = brow ? MTOT : DMODEL;

    const int tid  = threadIdx.x;
    const int wave = tid >> 6, lane = tid & 63, quad = lane >> 4, l16 = lane & 15;
    const int wm = wave >> 1, wn = wave & 1;
    const int srow = lane >> 3, pch = lane & 7;

    f32x4 acc[4][4];
#pragma unroll
    for (int i = 0; i < 4; ++i)
#pragma unroll
        for (int j = 0; j < 4; ++j)
#pragma unroll
            for (int r = 0; r < 4; ++r) acc[i][j][r] = 0.f;

    for (int k0 = 0; k0 < DMODEL; k0 += 64) {
#pragma unroll
        for (int rr = 0; rr < 4; ++rr) {
            int row = rr * 32 + wave * 8 + srow;
            int c   = pch ^ (row & 7);
            gload16(A + (size_t)(m0 + row) * DMODEL + k0 + c * 8,
                    &As[(size_t)(rr * 32 + wave * 8) * 64]);
        }
#pragma unroll
        for (int rr = 0; rr < 4; ++rr) {
            int row = rr * 32 + wave * 8 + srow;
            int c   = pch ^ (row & 7);
            gload16(Bt + (size_t)(n0 + row) * DMODEL + k0 + c * 8,
                    &Bs[(size_t)(rr * 32 + wave * 8) * 64]);
        }
        __syncthreads();

#pragma unroll
        for (int hh = 0; hh < 2; ++hh) {
            bf16x8 af[4], bfr[4];
#pragma unroll
            for (int t = 0; t < 4; ++t) {
                int ra = wm * 64 + t * 16 + l16;
                int pa = (hh * 4 + quad) ^ (l16 & 7);
                af[t] = ld_frag(&As[(size_t)ra * 64 + pa * 8]);
                int rb = wn * 64 + t * 16 + l16;
                bfr[t] = ld_frag(&Bs[(size_t)rb * 64 + pa * 8]);
            }
#pragma unroll
            for (int i = 0; i < 4; ++i)
#pragma unroll
                for (int j = 0; j < 4; ++j)
                    acc[i][j] = __builtin_amdgcn_mfma_f32_16x16x32_bf16(af[i], bfr[j], acc[i][j], 0, 0, 0);
        }
        __syncthreads();
    }

#pragma unroll
    for (int j = 0; j < 4; ++j) {
        int n = n0 + wn * 64 + j * 16 + l16;
        float bcol = brow ? 0.f : bias[n];
#pragma unroll
        for (int i = 0; i < 4; ++i) {
#pragma unroll
            for (int r = 0; r < 4; ++r) {
                int m = m0 + wm * 64 + i * 16 + quad * 4 + r;
                float bvv = brow ? bias[m] : bcol;
                out[(size_t)m * ostride + n] = f2bf((acc[i][j][r] + bvv) * scale);
            }
        }
    }
}

// ---------------------------------------------------------------------------
// Out-GEMM: 64x128 tile (grid 128 x 8 = 1024 blocks), fp32 output + bias.
// Waves 2x2: wave computes 32x64. A = Ob (bf16), Bt = Wo (bf16).
// ---------------------------------------------------------------------------
__global__ __launch_bounds__(256)
void out_gemm(const unsigned short* __restrict__ A, const unsigned short* __restrict__ Bt,
              const float* __restrict__ bias, float* __restrict__ C)
{
    __shared__ unsigned short As[64 * 64];
    __shared__ unsigned short Bs[128 * 64];

    const int tid  = threadIdx.x;
    const int wave = tid >> 6, lane = tid & 63, quad = lane >> 4, l16 = lane & 15;
    const int wm = wave >> 1, wn = wave & 1;
    const int m0 = blockIdx.x * 64, n0 = blockIdx.y * 128;
    const int srow = lane >> 3, pch = lane & 7;

    f32x4 acc[2][4];
#pragma unroll
    for (int i = 0; i < 2; ++i)
#pragma unroll
        for (int j = 0; j < 4; ++j)
#pragma unroll
            for (int r = 0; r < 4; ++r) acc[i][j][r] = 0.f;

    for (int k0 = 0; k0 < DMODEL; k0 += 64) {
#pragma unroll
        for (int rr = 0; rr < 2; ++rr) {
            int row = rr * 32 + wave * 8 + srow;
            int c   = pch ^ (row & 7);
            gload16(A + (size_t)(m0 + row) * DMODEL + k0 + c * 8,
                    &As[(size_t)(rr * 32 + wave * 8) * 64]);
        }
#pragma unroll
        for (int rr = 0; rr < 4; ++rr) {
            int row = rr * 32 + wave * 8 + srow;
            int c   = pch ^ (row & 7);
            gload16(Bt + (size_t)(n0 + row) * DMODEL + k0 + c * 8,
                    &Bs[(size_t)(rr * 32 + wave * 8) * 64]);
        }
        __syncthreads();

#pragma unroll
        for (int hh = 0; hh < 2; ++hh) {
            bf16x8 af[2], bfr[4];
            int pa_base = hh * 4 + quad;
#pragma unroll
            for (int t = 0; t < 2; ++t) {
                int ra = wm * 32 + t * 16 + l16;
                af[t] = ld_frag(&As[(size_t)ra * 64 + ((pa_base ^ (l16 & 7)) * 8)]);
            }
#pragma unroll
            for (int t = 0; t < 4; ++t) {
                int rb = wn * 64 + t * 16 + l16;
                bfr[t] = ld_frag(&Bs[(size_t)rb * 64 + ((pa_base ^ (l16 & 7)) * 8)]);
            }
#pragma unroll
            for (int i = 0; i < 2; ++i)
#pragma unroll
                for (int j = 0; j < 4; ++j)
                    acc[i][j] = __builtin_amdgcn_mfma_f32_16x16x32_bf16(af[i], bfr[j], acc[i][j], 0, 0, 0);
        }
        __syncthreads();
    }

#pragma unroll
    for (int j = 0; j < 4; ++j) {
        int n = n0 + wn * 64 + j * 16 + l16;
        float bcol = bias[n];
#pragma unroll
        for (int i = 0; i < 2; ++i) {
#pragma unroll
            for (int r = 0; r < 4; ++r) {
                int m = m0 + wm * 32 + i * 16 + quad * 4 + r;
                C[(size_t)m * DMODEL + n] = acc[i][j][r] + bcol;
            }
        }
    }
}

// ---------------------------------------------------------------------------
// Flash attention (unchanged from R4).
// ---------------------------------------------------------------------------
__global__ __launch_bounds__(256)
void attn_kernel(const unsigned short* __restrict__ Qb, const unsigned short* __restrict__ Kb,
                 const unsigned short* __restrict__ VbT, unsigned short* __restrict__ Ob)
{
    __shared__ unsigned short Ks[64 * 64];
    __shared__ unsigned short Vt[64 * 64];
    __shared__ unsigned short Ps[4][32][72];

    const int tid  = threadIdx.x;
    const int wave = tid >> 6, lane = tid & 63, quad = lane >> 4, l16 = lane & 15;
    const int q0 = blockIdx.x * 128, h = blockIdx.y, b = blockIdx.z;
    const int sw = l16 & 7;

    bf16x8 qf[2][2];
    const unsigned short* qbase = Qb + (size_t)(b * SEQ + q0 + wave * 32) * DMODEL + h * DK;
#pragma unroll
    for (int qs = 0; qs < 2; ++qs)
#pragma unroll
        for (int hh = 0; hh < 2; ++hh)
            qf[qs][hh] = ld_frag(qbase + (size_t)(qs * 16 + l16) * DMODEL + hh * 32 + quad * 8);

    f32x4 zero4;
#pragma unroll
    for (int r = 0; r < 4; ++r) zero4[r] = 0.f;

    f32x4 o[2][4], lacc[2];
#pragma unroll
    for (int qs = 0; qs < 2; ++qs) {
        lacc[qs] = zero4;
#pragma unroll
        for (int t = 0; t < 4; ++t) o[qs][t] = zero4;
    }

    bf16x8 onesf;
    {
        V8 u;
#pragma unroll
        for (int j = 0; j < 8; ++j) u.s[j] = 0x3F80;
        onesf = __builtin_bit_cast(bf16x8, u.v);
    }

    const int sr  = lane >> 3;
    const int pch = lane & 7;

    for (int kt = 0; kt < SEQ; kt += 64) {
        __syncthreads();
#pragma unroll
        for (int i = 0; i < 2; ++i) {
            int blk = wave * 2 + i;
            int row = blk * 8 + sr;
            int c   = pch ^ (row & 7);
            int key = 4 * (row & 15) + (row >> 4);
            gload16(Kb + (size_t)(b * SEQ + kt + key) * DMODEL + h * DK + c * 8,
                    &Ks[(size_t)blk * 512]);
            gload16(VbT + (size_t)(h * DK + row) * MTOT + b * SEQ + kt + c * 8,
                    &Vt[(size_t)blk * 512]);
        }
        __syncthreads();

        f32x4 s[2][4];
#pragma unroll
        for (int c = 0; c < 4; ++c) {
            bf16x8 kb0 = ld_frag(&Ks[(size_t)(c * 16 + l16) * 64 + ((quad ^ sw) * 8)]);
            bf16x8 kb1 = ld_frag(&Ks[(size_t)(c * 16 + l16) * 64 + (((4 + quad) ^ sw) * 8)]);
            s[0][c] = __builtin_amdgcn_mfma_f32_16x16x32_bf16(qf[0][1], kb1,
                      __builtin_amdgcn_mfma_f32_16x16x32_bf16(qf[0][0], kb0, zero4, 0, 0, 0), 0, 0, 0);
            s[1][c] = __builtin_amdgcn_mfma_f32_16x16x32_bf16(qf[1][1], kb1,
                      __builtin_amdgcn_mfma_f32_16x16x32_bf16(qf[1][0], kb0, zero4, 0, 0, 0), 0, 0, 0);
        }

#pragma unroll
        for (int qs = 0; qs < 2; ++qs)
#pragma unroll
            for (int r = 0; r < 4; ++r) {
                float p0 = __builtin_amdgcn_exp2f(s[qs][0][r]);
                float p1 = __builtin_amdgcn_exp2f(s[qs][1][r]);
                float p2 = __builtin_amdgcn_exp2f(s[qs][2][r]);
                float p3 = __builtin_amdgcn_exp2f(s[qs][3][r]);
                uint2 pk;
                pk.x = pack_bf(p0, p1);
                pk.y = pack_bf(p2, p3);
                *(uint2*)&Ps[wave][qs * 16 + quad * 4 + r][4 * l16] = pk;
            }

        bf16x8 pf[2][2];
#pragma unroll
        for (int qs = 0; qs < 2; ++qs)
#pragma unroll
            for (int hh = 0; hh < 2; ++hh)
                pf[qs][hh] = ld_frag(&Ps[wave][qs * 16 + l16][hh * 32 + quad * 8]);

#pragma unroll
        for (int qs = 0; qs < 2; ++qs) {
            lacc[qs] = __builtin_amdgcn_mfma_f32_16x16x32_bf16(pf[qs][0], onesf, lacc[qs], 0, 0, 0);
            lacc[qs] = __builtin_amdgcn_mfma_f32_16x16x32_bf16(pf[qs][1], onesf, lacc[qs], 0, 0, 0);
        }

#pragma unroll
        for (int t = 0; t < 4; ++t)
#pragma unroll
            for (int hh = 0; hh < 2; ++hh) {
                bf16x8 vb = ld_frag(&Vt[(size_t)(t * 16 + l16) * 64 + (((hh * 4 + quad) ^ sw) * 8)]);
                o[0][t] = __builtin_amdgcn_mfma_f32_16x16x32_bf16(pf[0][hh], vb, o[0][t], 0, 0, 0);
                o[1][t] = __builtin_amdgcn_mfma_f32_16x16x32_bf16(pf[1][hh], vb, o[1][t], 0, 0, 0);
            }
    }

#pragma unroll
    for (int qs = 0; qs < 2; ++qs) {
        float inv[4];
#pragma unroll
        for (int r = 0; r < 4; ++r) inv[r] = 1.f / lacc[qs][r];
#pragma unroll
        for (int t = 0; t < 4; ++t) {
            int d = h * DK + t * 16 + l16;
#pragma unroll
            for (int r = 0; r < 4; ++r) {
                int q = q0 + wave * 32 + qs * 16 + quad * 4 + r;
                Ob[(size_t)(b * SEQ + q) * DMODEL + d] = f2bf(o[qs][t][r] * inv[r]);
            }
        }
    }
}

// ---------------------------------------------------------------------------
extern "C" void kernel_launch(void* const* d_in, const int* in_sizes, int n_in,
                              void* d_out, int out_size, void* d_ws, size_t ws_size,
                              hipStream_t stream)
{
    const float* query  = (const float*)d_in[0];
    const float* key_in = (const float*)d_in[1];
    const float* value  = (const float*)d_in[2];
    const float* Wq = (const float*)d_in[3];
    const float* bq = (const float*)d_in[4];
    const float* Wk = (const float*)d_in[5];
    const float* bk = (const float*)d_in[6];
    const float* Wv = (const float*)d_in[7];
    const float* bv = (const float*)d_in[8];
    const float* Wo = (const float*)d_in[9];
    const float* bo = (const float*)d_in[10];

    const size_t NM = (size_t)MTOT * DMODEL;     // 8.39M elems
    const size_t NW = (size_t)DMODEL * DMODEL;   // 1.05M elems
    const float qscale = 0.18033688f;            // log2(e)/sqrt(d_k)
    dim3 bb(256);

    const size_t need_primary = (6 * NM + 4 * NW) * 2;   // 109.1 MB

    if (ws_size >= need_primary) {
        // ---- primary: fused QKV, high-occupancy out GEMM ----
        unsigned short* Qa  = (unsigned short*)d_ws;
        unsigned short* Ka  = Qa + NM;
        unsigned short* Va  = Ka + NM;
        unsigned short* Qb  = Va + NM;
        unsigned short* Kb  = Qb + NM;
        unsigned short* VbT = Kb + NM;
        unsigned short* Wqb = VbT + NM;
        unsigned short* Wkb = Wqb + NW;
        unsigned short* Wvb = Wkb + NW;
        unsigned short* Wob = Wvb + NW;
        unsigned short* Ob  = Qa;   // Qa dead after qkv_gemm

        conv3<<<dim3(4096, 1, 3), bb, 0, stream>>>(query, key_in, value, Qa, Ka, Va);
        conv4<<<dim3(512, 1, 4), bb, 0, stream>>>(Wq, Wk, Wv, Wo, Wqb, Wkb, Wvb, Wob);

        qkv_gemm<<<dim3(MTOT / 128, DMODEL / 128, 3), bb, 0, stream>>>(
            Qa, Ka, Va, Wqb, Wkb, Wvb, bq, bk, bv, Qb, Kb, VbT, qscale);

        attn_kernel<<<dim3(SEQ / 128, NH, BSZ), bb, 0, stream>>>(Qb, Kb, VbT, Ob);

        out_gemm<<<dim3(MTOT / 64, DMODEL / 128), bb, 0, stream>>>(Ob, Wob, bo, (float*)d_out);
    } else {
        // ---- fallback: R4 sequential path (69.2 MB) ----
        unsigned short* tmpA = (unsigned short*)d_ws;
        unsigned short* tmpW = tmpA + NM;
        unsigned short* Qb   = tmpW + NW;
        unsigned short* Kb   = Qb + NM;
        unsigned short* VbT  = Kb + NM;
        unsigned short* Ob   = tmpA;

        const int gcA = (int)(NM / 8 / 256);
        const int gcW = (int)(NW / 8 / 256);
        dim3 gg(MTOT / 128, DMODEL / 128);
        dim3 gv(DMODEL / 128, MTOT / 128);

        conv_bf16<<<gcA, bb, 0, stream>>>(query, tmpA);
        conv_bf16<<<gcW, bb, 0, stream>>>(Wq, tmpW);
        gemm_bt16<0, 0><<<gg, bb, 0, stream>>>(tmpA, tmpW, bq, Qb, MTOT, DMODEL, DMODEL, qscale);

        conv_bf16<<<gcA, bb, 0, stream>>>(key_in, tmpA);
        conv_bf16<<<gcW, bb, 0, stream>>>(Wk, tmpW);
        gemm_bt16<0, 0><<<gg, bb, 0, stream>>>(tmpA, tmpW, bk, Kb, MTOT, DMODEL, DMODEL, 1.0f);

        conv_bf16<<<gcA, bb, 0, stream>>>(value, tmpA);
        conv_bf16<<<gcW, bb, 0, stream>>>(Wv, tmpW);
        gemm_bt16<0, 1><<<gv, bb, 0, stream>>>(tmpW, tmpA, bv, VbT, DMODEL, MTOT, DMODEL, 1.0f);

        attn_kernel<<<dim3(SEQ / 128, NH, BSZ), bb, 0, stream>>>(Qb, Kb, VbT, Ob);

        conv_bf16<<<gcW, bb, 0, stream>>>(Wo, tmpW);
        out_gemm<<<dim3(MTOT / 64, DMODEL / 128), bb, 0, stream>>>(Ob, tmpW, bo, (float*)d_out);
    }
}

// Round 6
// 364.599 us; speedup vs baseline: 1.0138x; 1.0138x over previous
//
#include <hip/hip_runtime.h>

// MHA: B=4, S=2048, d_model=1024, H=16, d_k=64
// Primary path (ws >= 109 MB): conv3(activations) + conv4(weights) ->
//   fused QKV GEMM (grid z=3, 1536 blocks) -> attn -> out GEMM (128x128 tile).
// Fallback (small ws): R4 sequential path.

#define DMODEL 1024
#define DK     64
#define NH     16
#define BSZ    4
#define SEQ    2048
#define MTOT   (BSZ * SEQ)   // 8192

typedef __attribute__((ext_vector_type(8))) __bf16 bf16x8;
typedef __attribute__((ext_vector_type(4))) float  f32x4;

__device__ inline unsigned short f2bf(float x) {
    union { float f; unsigned u; } v; v.f = x;
    unsigned r = v.u + 0x7FFF + ((v.u >> 16) & 1u);   // RNE
    return (unsigned short)(r >> 16);
}

__device__ inline bf16x8 ld_frag(const unsigned short* p) {
    return __builtin_bit_cast(bf16x8, *(const int4*)p);
}

union V8 { int4 v; unsigned short s[8]; };

__device__ inline void gload16(const unsigned short* g, unsigned short* l) {
    __builtin_amdgcn_global_load_lds(
        (const __attribute__((address_space(1))) void*)g,
        (__attribute__((address_space(3))) void*)l, 16, 0, 0);
}

__device__ inline unsigned pack_bf(float lo, float hi) {
    unsigned b0 = __builtin_bit_cast(unsigned, lo) + 0x8000u;
    unsigned b1 = __builtin_bit_cast(unsigned, hi) + 0x8000u;
    return __builtin_amdgcn_perm(b1, b0, 0x07060302u);
}

// ---------------------------------------------------------------------------
// fp32 -> bf16 converters
// ---------------------------------------------------------------------------
__device__ inline void conv_body(const float* __restrict__ src,
                                 unsigned short* __restrict__ dst, int i)
{
    const float4* s = (const float4*)src + (size_t)i * 2;
    float4 a = s[0], b = s[1];
    V8 u;
    u.s[0] = f2bf(a.x); u.s[1] = f2bf(a.y); u.s[2] = f2bf(a.z); u.s[3] = f2bf(a.w);
    u.s[4] = f2bf(b.x); u.s[5] = f2bf(b.y); u.s[6] = f2bf(b.z); u.s[7] = f2bf(b.w);
    ((int4*)dst)[i] = u.v;
}

__global__ __launch_bounds__(256)
void conv_bf16(const float* __restrict__ src, unsigned short* __restrict__ dst)
{
    conv_body(src, dst, blockIdx.x * 256 + threadIdx.x);
}

__global__ __launch_bounds__(256)
void conv3(const float* __restrict__ s0, const float* __restrict__ s1,
           const float* __restrict__ s2, unsigned short* __restrict__ d0,
           unsigned short* __restrict__ d1, unsigned short* __restrict__ d2)
{
    int z = blockIdx.z;
    const float* s = (z == 0) ? s0 : (z == 1) ? s1 : s2;
    unsigned short* d = (z == 0) ? d0 : (z == 1) ? d1 : d2;
    conv_body(s, d, blockIdx.x * 256 + threadIdx.x);
}

__global__ __launch_bounds__(256)
void conv4(const float* __restrict__ s0, const float* __restrict__ s1,
           const float* __restrict__ s2, const float* __restrict__ s3,
           unsigned short* __restrict__ d0, unsigned short* __restrict__ d1,
           unsigned short* __restrict__ d2, unsigned short* __restrict__ d3)
{
    int z = blockIdx.z;
    const float* s = (z == 0) ? s0 : (z == 1) ? s1 : (z == 2) ? s2 : s3;
    unsigned short* d = (z == 0) ? d0 : (z == 1) ? d1 : (z == 2) ? d2 : d3;
    conv_body(s, d, blockIdx.x * 256 + threadIdx.x);
}

// ---------------------------------------------------------------------------
// bf16 GEMM: 128x128 tile, gload16 staging, XOR swizzle. The workhorse.
// ---------------------------------------------------------------------------
template<int OUT_F32, int BIAS_ROW>
__global__ __launch_bounds__(256)
void gemm_bt16(const unsigned short* __restrict__ A, const unsigned short* __restrict__ Bt,
               const float* __restrict__ bias, void* __restrict__ Cout,
               int Mdim, int Ndim, int Kdim, float scale)
{
    __shared__ unsigned short As[128 * 64];
    __shared__ unsigned short Bs[128 * 64];

    const int tid  = threadIdx.x;
    const int wave = tid >> 6, lane = tid & 63, quad = lane >> 4, l16 = lane & 15;
    const int wm = wave >> 1, wn = wave & 1;
    const int m0 = blockIdx.x * 128, n0 = blockIdx.y * 128;
    const int srow = lane >> 3, pch = lane & 7;

    f32x4 acc[4][4];
#pragma unroll
    for (int i = 0; i < 4; ++i)
#pragma unroll
        for (int j = 0; j < 4; ++j)
#pragma unroll
            for (int r = 0; r < 4; ++r) acc[i][j][r] = 0.f;

    for (int k0 = 0; k0 < Kdim; k0 += 64) {
#pragma unroll
        for (int rr = 0; rr < 4; ++rr) {
            int row = rr * 32 + wave * 8 + srow;
            int c   = pch ^ (row & 7);
            gload16(A + (size_t)(m0 + row) * Kdim + k0 + c * 8,
                    &As[(size_t)(rr * 32 + wave * 8) * 64]);
        }
#pragma unroll
        for (int rr = 0; rr < 4; ++rr) {
            int row = rr * 32 + wave * 8 + srow;
            int c   = pch ^ (row & 7);
            gload16(Bt + (size_t)(n0 + row) * Kdim + k0 + c * 8,
                    &Bs[(size_t)(rr * 32 + wave * 8) * 64]);
        }
        __syncthreads();

#pragma unroll
        for (int hh = 0; hh < 2; ++hh) {
            bf16x8 af[4], bfr[4];
#pragma unroll
            for (int t = 0; t < 4; ++t) {
                int ra = wm * 64 + t * 16 + l16;
                int pa = (hh * 4 + quad) ^ (l16 & 7);
                af[t] = ld_frag(&As[(size_t)ra * 64 + pa * 8]);
                int rb = wn * 64 + t * 16 + l16;
                bfr[t] = ld_frag(&Bs[(size_t)rb * 64 + pa * 8]);
            }
#pragma unroll
            for (int i = 0; i < 4; ++i)
#pragma unroll
                for (int j = 0; j < 4; ++j)
                    acc[i][j] = __builtin_amdgcn_mfma_f32_16x16x32_bf16(af[i], bfr[j], acc[i][j], 0, 0, 0);
        }
        __syncthreads();
    }

#pragma unroll
    for (int j = 0; j < 4; ++j) {
        int n = n0 + wn * 64 + j * 16 + l16;
        float bcol = BIAS_ROW ? 0.f : bias[n];
#pragma unroll
        for (int i = 0; i < 4; ++i) {
#pragma unroll
            for (int r = 0; r < 4; ++r) {
                int m = m0 + wm * 64 + i * 16 + quad * 4 + r;
                float bv = BIAS_ROW ? bias[m] : bcol;
                float val = (acc[i][j][r] + bv) * scale;
                if (OUT_F32) ((float*)Cout)[(size_t)m * Ndim + n] = val;
                else ((unsigned short*)Cout)[(size_t)m * Ndim + n] = f2bf(val);
            }
        }
    }
}

// ---------------------------------------------------------------------------
// Fused QKV projection GEMM. grid (64, 8, 3):
//  z=0: Qb  = (query@Wq^T + bq) * qscale
//  z=1: Kb  =  key  @Wk^T + bk
//  z=2: VbT = (Wv@value^T + bv[row]), transposed block mapping, stride MTOT
// ---------------------------------------------------------------------------
__global__ __launch_bounds__(256)
void qkv_gemm(const unsigned short* __restrict__ Qa, const unsigned short* __restrict__ Ka,
              const unsigned short* __restrict__ Va,
              const unsigned short* __restrict__ Wqb, const unsigned short* __restrict__ Wkb,
              const unsigned short* __restrict__ Wvb,
              const float* __restrict__ bq, const float* __restrict__ bk,
              const float* __restrict__ bv,
              unsigned short* __restrict__ Qb, unsigned short* __restrict__ Kb,
              unsigned short* __restrict__ VbT, float qscale)
{
    __shared__ unsigned short As[128 * 64];
    __shared__ unsigned short Bs[128 * 64];

    const int z = blockIdx.z;
    const unsigned short* A  = (z == 0) ? Qa  : (z == 1) ? Ka  : Wvb;
    const unsigned short* Bt = (z == 0) ? Wqb : (z == 1) ? Wkb : Va;
    const float* bias        = (z == 0) ? bq  : (z == 1) ? bk  : bv;
    unsigned short* out      = (z == 0) ? Qb  : (z == 1) ? Kb  : VbT;
    const float scale  = (z == 0) ? qscale : 1.0f;
    const int brow     = (z == 2);
    const int m0       = brow ? blockIdx.y * 128 : blockIdx.x * 128;
    const int n0       = brow ? blockIdx.x * 128 : blockIdx.y * 128;
    const int ostride  = brow ? MTOT : DMODEL;

    const int tid  = threadIdx.x;
    const int wave = tid >> 6, lane = tid & 63, quad = lane >> 4, l16 = lane & 15;
    const int wm = wave >> 1, wn = wave & 1;
    const int srow = lane >> 3, pch = lane & 7;

    f32x4 acc[4][4];
#pragma unroll
    for (int i = 0; i < 4; ++i)
#pragma unroll
        for (int j = 0; j < 4; ++j)
#pragma unroll
            for (int r = 0; r < 4; ++r) acc[i][j][r] = 0.f;

    for (int k0 = 0; k0 < DMODEL; k0 += 64) {
#pragma unroll
        for (int rr = 0; rr < 4; ++rr) {
            int row = rr * 32 + wave * 8 + srow;
            int c   = pch ^ (row & 7);
            gload16(A + (size_t)(m0 + row) * DMODEL + k0 + c * 8,
                    &As[(size_t)(rr * 32 + wave * 8) * 64]);
        }
#pragma unroll
        for (int rr = 0; rr < 4; ++rr) {
            int row = rr * 32 + wave * 8 + srow;
            int c   = pch ^ (row & 7);
            gload16(Bt + (size_t)(n0 + row) * DMODEL + k0 + c * 8,
                    &Bs[(size_t)(rr * 32 + wave * 8) * 64]);
        }
        __syncthreads();

#pragma unroll
        for (int hh = 0; hh < 2; ++hh) {
            bf16x8 af[4], bfr[4];
#pragma unroll
            for (int t = 0; t < 4; ++t) {
                int ra = wm * 64 + t * 16 + l16;
                int pa = (hh * 4 + quad) ^ (l16 & 7);
                af[t] = ld_frag(&As[(size_t)ra * 64 + pa * 8]);
                int rb = wn * 64 + t * 16 + l16;
                bfr[t] = ld_frag(&Bs[(size_t)rb * 64 + pa * 8]);
            }
#pragma unroll
            for (int i = 0; i < 4; ++i)
#pragma unroll
                for (int j = 0; j < 4; ++j)
                    acc[i][j] = __builtin_amdgcn_mfma_f32_16x16x32_bf16(af[i], bfr[j], acc[i][j], 0, 0, 0);
        }
        __syncthreads();
    }

#pragma unroll
    for (int j = 0; j < 4; ++j) {
        int n = n0 + wn * 64 + j * 16 + l16;
        float bcol = brow ? 0.f : bias[n];
#pragma unroll
        for (int i = 0; i < 4; ++i) {
#pragma unroll
            for (int r = 0; r < 4; ++r) {
                int m = m0 + wm * 64 + i * 16 + quad * 4 + r;
                float bvv = brow ? bias[m] : bcol;
                out[(size_t)m * ostride + n] = f2bf((acc[i][j][r] + bvv) * scale);
            }
        }
    }
}

// ---------------------------------------------------------------------------
// Flash attention (unchanged from R4).
// ---------------------------------------------------------------------------
__global__ __launch_bounds__(256)
void attn_kernel(const unsigned short* __restrict__ Qb, const unsigned short* __restrict__ Kb,
                 const unsigned short* __restrict__ VbT, unsigned short* __restrict__ Ob)
{
    __shared__ unsigned short Ks[64 * 64];
    __shared__ unsigned short Vt[64 * 64];
    __shared__ unsigned short Ps[4][32][72];

    const int tid  = threadIdx.x;
    const int wave = tid >> 6, lane = tid & 63, quad = lane >> 4, l16 = lane & 15;
    const int q0 = blockIdx.x * 128, h = blockIdx.y, b = blockIdx.z;
    const int sw = l16 & 7;

    bf16x8 qf[2][2];
    const unsigned short* qbase = Qb + (size_t)(b * SEQ + q0 + wave * 32) * DMODEL + h * DK;
#pragma unroll
    for (int qs = 0; qs < 2; ++qs)
#pragma unroll
        for (int hh = 0; hh < 2; ++hh)
            qf[qs][hh] = ld_frag(qbase + (size_t)(qs * 16 + l16) * DMODEL + hh * 32 + quad * 8);

    f32x4 zero4;
#pragma unroll
    for (int r = 0; r < 4; ++r) zero4[r] = 0.f;

    f32x4 o[2][4], lacc[2];
#pragma unroll
    for (int qs = 0; qs < 2; ++qs) {
        lacc[qs] = zero4;
#pragma unroll
        for (int t = 0; t < 4; ++t) o[qs][t] = zero4;
    }

    bf16x8 onesf;
    {
        V8 u;
#pragma unroll
        for (int j = 0; j < 8; ++j) u.s[j] = 0x3F80;
        onesf = __builtin_bit_cast(bf16x8, u.v);
    }

    const int sr  = lane >> 3;
    const int pch = lane & 7;

    for (int kt = 0; kt < SEQ; kt += 64) {
        __syncthreads();
#pragma unroll
        for (int i = 0; i < 2; ++i) {
            int blk = wave * 2 + i;
            int row = blk * 8 + sr;
            int c   = pch ^ (row & 7);
            int key = 4 * (row & 15) + (row >> 4);
            gload16(Kb + (size_t)(b * SEQ + kt + key) * DMODEL + h * DK + c * 8,
                    &Ks[(size_t)blk * 512]);
            gload16(VbT + (size_t)(h * DK + row) * MTOT + b * SEQ + kt + c * 8,
                    &Vt[(size_t)blk * 512]);
        }
        __syncthreads();

        f32x4 s[2][4];
#pragma unroll
        for (int c = 0; c < 4; ++c) {
            bf16x8 kb0 = ld_frag(&Ks[(size_t)(c * 16 + l16) * 64 + ((quad ^ sw) * 8)]);
            bf16x8 kb1 = ld_frag(&Ks[(size_t)(c * 16 + l16) * 64 + (((4 + quad) ^ sw) * 8)]);
            s[0][c] = __builtin_amdgcn_mfma_f32_16x16x32_bf16(qf[0][1], kb1,
                      __builtin_amdgcn_mfma_f32_16x16x32_bf16(qf[0][0], kb0, zero4, 0, 0, 0), 0, 0, 0);
            s[1][c] = __builtin_amdgcn_mfma_f32_16x16x32_bf16(qf[1][1], kb1,
                      __builtin_amdgcn_mfma_f32_16x16x32_bf16(qf[1][0], kb0, zero4, 0, 0, 0), 0, 0, 0);
        }

#pragma unroll
        for (int qs = 0; qs < 2; ++qs)
#pragma unroll
            for (int r = 0; r < 4; ++r) {
                float p0 = __builtin_amdgcn_exp2f(s[qs][0][r]);
                float p1 = __builtin_amdgcn_exp2f(s[qs][1][r]);
                float p2 = __builtin_amdgcn_exp2f(s[qs][2][r]);
                float p3 = __builtin_amdgcn_exp2f(s[qs][3][r]);
                uint2 pk;
                pk.x = pack_bf(p0, p1);
                pk.y = pack_bf(p2, p3);
                *(uint2*)&Ps[wave][qs * 16 + quad * 4 + r][4 * l16] = pk;
            }

        bf16x8 pf[2][2];
#pragma unroll
        for (int qs = 0; qs < 2; ++qs)
#pragma unroll
            for (int hh = 0; hh < 2; ++hh)
                pf[qs][hh] = ld_frag(&Ps[wave][qs * 16 + l16][hh * 32 + quad * 8]);

#pragma unroll
        for (int qs = 0; qs < 2; ++qs) {
            lacc[qs] = __builtin_amdgcn_mfma_f32_16x16x32_bf16(pf[qs][0], onesf, lacc[qs], 0, 0, 0);
            lacc[qs] = __builtin_amdgcn_mfma_f32_16x16x32_bf16(pf[qs][1], onesf, lacc[qs], 0, 0, 0);
        }

#pragma unroll
        for (int t = 0; t < 4; ++t)
#pragma unroll
            for (int hh = 0; hh < 2; ++hh) {
                bf16x8 vb = ld_frag(&Vt[(size_t)(t * 16 + l16) * 64 + (((hh * 4 + quad) ^ sw) * 8)]);
                o[0][t] = __builtin_amdgcn_mfma_f32_16x16x32_bf16(pf[0][hh], vb, o[0][t], 0, 0, 0);
                o[1][t] = __builtin_amdgcn_mfma_f32_16x16x32_bf16(pf[1][hh], vb, o[1][t], 0, 0, 0);
            }
    }

#pragma unroll
    for (int qs = 0; qs < 2; ++qs) {
        float inv[4];
#pragma unroll
        for (int r = 0; r < 4; ++r) inv[r] = 1.f / lacc[qs][r];
#pragma unroll
        for (int t = 0; t < 4; ++t) {
            int d = h * DK + t * 16 + l16;
#pragma unroll
            for (int r = 0; r < 4; ++r) {
                int q = q0 + wave * 32 + qs * 16 + quad * 4 + r;
                Ob[(size_t)(b * SEQ + q) * DMODEL + d] = f2bf(o[qs][t][r] * inv[r]);
            }
        }
    }
}

// ---------------------------------------------------------------------------
extern "C" void kernel_launch(void* const* d_in, const int* in_sizes, int n_in,
                              void* d_out, int out_size, void* d_ws, size_t ws_size,
                              hipStream_t stream)
{
    const float* query  = (const float*)d_in[0];
    const float* key_in = (const float*)d_in[1];
    const float* value  = (const float*)d_in[2];
    const float* Wq = (const float*)d_in[3];
    const float* bq = (const float*)d_in[4];
    const float* Wk = (const float*)d_in[5];
    const float* bk = (const float*)d_in[6];
    const float* Wv = (const float*)d_in[7];
    const float* bv = (const float*)d_in[8];
    const float* Wo = (const float*)d_in[9];
    const float* bo = (const float*)d_in[10];

    const size_t NM = (size_t)MTOT * DMODEL;     // 8.39M elems
    const size_t NW = (size_t)DMODEL * DMODEL;   // 1.05M elems
    const float qscale = 0.18033688f;            // log2(e)/sqrt(d_k)
    dim3 bb(256);

    const size_t need_primary = (6 * NM + 4 * NW) * 2;   // 109.1 MB

    if (ws_size >= need_primary) {
        unsigned short* Qa  = (unsigned short*)d_ws;
        unsigned short* Ka  = Qa + NM;
        unsigned short* Va  = Ka + NM;
        unsigned short* Qb  = Va + NM;
        unsigned short* Kb  = Qb + NM;
        unsigned short* VbT = Kb + NM;
        unsigned short* Wqb = VbT + NM;
        unsigned short* Wkb = Wqb + NW;
        unsigned short* Wvb = Wkb + NW;
        unsigned short* Wob = Wvb + NW;
        unsigned short* Ob  = Qa;   // Qa dead after qkv_gemm

        conv3<<<dim3(4096, 1, 3), bb, 0, stream>>>(query, key_in, value, Qa, Ka, Va);
        conv4<<<dim3(512, 1, 4), bb, 0, stream>>>(Wq, Wk, Wv, Wo, Wqb, Wkb, Wvb, Wob);

        qkv_gemm<<<dim3(MTOT / 128, DMODEL / 128, 3), bb, 0, stream>>>(
            Qa, Ka, Va, Wqb, Wkb, Wvb, bq, bk, bv, Qb, Kb, VbT, qscale);

        attn_kernel<<<dim3(SEQ / 128, NH, BSZ), bb, 0, stream>>>(Qb, Kb, VbT, Ob);

        gemm_bt16<1, 0><<<dim3(MTOT / 128, DMODEL / 128), bb, 0, stream>>>(
            Ob, Wob, bo, (float*)d_out, MTOT, DMODEL, DMODEL, 1.0f);
    } else {
        // ---- fallback: sequential path (69.2 MB) ----
        unsigned short* tmpA = (unsigned short*)d_ws;
        unsigned short* tmpW = tmpA + NM;
        unsigned short* Qb   = tmpW + NW;
        unsigned short* Kb   = Qb + NM;
        unsigned short* VbT  = Kb + NM;
        unsigned short* Ob   = tmpA;

        const int gcA = (int)(NM / 8 / 256);
        const int gcW = (int)(NW / 8 / 256);
        dim3 gg(MTOT / 128, DMODEL / 128);
        dim3 gv(DMODEL / 128, MTOT / 128);

        conv_bf16<<<gcA, bb, 0, stream>>>(query, tmpA);
        conv_bf16<<<gcW, bb, 0, stream>>>(Wq, tmpW);
        gemm_bt16<0, 0><<<gg, bb, 0, stream>>>(tmpA, tmpW, bq, Qb, MTOT, DMODEL, DMODEL, qscale);

        conv_bf16<<<gcA, bb, 0, stream>>>(key_in, tmpA);
        conv_bf16<<<gcW, bb, 0, stream>>>(Wk, tmpW);
        gemm_bt16<0, 0><<<gg, bb, 0, stream>>>(tmpA, tmpW, bk, Kb, MTOT, DMODEL, DMODEL, 1.0f);

        conv_bf16<<<gcA, bb, 0, stream>>>(value, tmpA);
        conv_bf16<<<gcW, bb, 0, stream>>>(Wv, tmpW);
        gemm_bt16<0, 1><<<gv, bb, 0, stream>>>(tmpW, tmpA, bv, VbT, DMODEL, MTOT, DMODEL, 1.0f);

        attn_kernel<<<dim3(SEQ / 128, NH, BSZ), bb, 0, stream>>>(Qb, Kb, VbT, Ob);

        conv_bf16<<<gcW, bb, 0, stream>>>(Wo, tmpW);
        gemm_bt16<1, 0><<<gg, bb, 0, stream>>>(Ob, tmpW, bo, (float*)d_out, MTOT, DMODEL, DMODEL, 1.0f);
    }
}